// Round 3
// baseline (443.070 us; speedup 1.0000x reference)
//
#include <hip/hip_runtime.h>

#define KW 11
#define PAD 5
#define TW 32
#define TH 32
#define IW 42             // TW + KW - 1
#define IH 42
#define SPITCH 44         // input tile pitch (floats); 44 % 32 = 12 -> uniform b128 windows
#define HPITCH 36         // h-array pitch (floats);   36 % 32 = 4  -> uniform b128 windows
#define IMH 512
#define IMW 512

typedef float f4 __attribute__((ext_vector_type(4)));

__global__ __launch_bounds__(256, 3) void ssim_main(
    const float* __restrict__ img1, const float* __restrict__ img2,
    const float* __restrict__ window, double* __restrict__ acc,
    unsigned* __restrict__ counter, float* __restrict__ out,
    unsigned nblocks, double inv_n)
{
    __shared__ float s1[IH * SPITCH];
    __shared__ float s2[IH * SPITCH];
    __shared__ float h1[IH * HPITCH];
    __shared__ float h2[IH * HPITCH];
    __shared__ float h11[IH * HPITCH];
    __shared__ float h22[IH * HPITCH];
    __shared__ float h12[IH * HPITCH];
    __shared__ float g[KW];
    __shared__ float wsum[4];

    const int t = threadIdx.x;

    // Separable 1D Gaussian = row-sums of the 2D window (columns sum to 1).
    if (t < KW) {
        float s = 0.f;
        for (int j = 0; j < KW; ++j) s += window[(t * KW + j) * 3];
        g[t] = s;
    }

    const int plane = blockIdx.z;
    const size_t base = (size_t)plane * IMH * IMW;
    const int ix0 = blockIdx.x * TW - PAD;
    const int iy0 = blockIdx.y * TH - PAD;

    // ---- Phase 0: stage inputs (zero-padded at borders), scalar b32 writes.
    for (int idx = t; idx < IH * IW; idx += 256) {
        int r = idx / IW, c = idx - r * IW;
        int gr = iy0 + r, gc = ix0 + c;
        float v1 = 0.f, v2 = 0.f;
        if (gr >= 0 && gr < IMH && gc >= 0 && gc < IMW) {
            size_t o = base + (size_t)gr * IMW + gc;
            v1 = img1[o];
            v2 = img2[o];
        }
        s1[r * SPITCH + c] = v1;
        s2[r * SPITCH + c] = v2;
    }
    __syncthreads();

    float wg[KW];
#pragma unroll
    for (int j = 0; j < KW; ++j) wg[j] = g[j];   // broadcast reads, conflict-free

    // ---- Phase 1: horizontal 11-tap; 168 tasks of 8 output cols each.
    if (t < IH * 4) {
        const int r = t >> 2, q = t & 3;          // row 0..41, col-octet 0..3
        const float* p1 = &s1[r * SPITCH + q * 8];
        const float* p2 = &s2[r * SPITCH + q * 8];
        f4 A[5], B[5];
#pragma unroll
        for (int o = 0; o < 5; ++o) {
            A[o] = *(const f4*)(p1 + o * 4);      // 16B aligned: pitch,q*8 mult of 4
            B[o] = *(const f4*)(p2 + o * 4);
        }
#define X1(c) (A[(c) >> 2][(c) & 3])
#define X2(c) (B[(c) >> 2][(c) & 3])
        float p11[18], p22[18], p12[18];
#pragma unroll
        for (int c = 0; c < 18; ++c) {
            float a = X1(c), b = X2(c);
            p11[c] = a * a;
            p22[c] = b * b;
            p12[c] = a * b;
        }
        float m1[8], m2[8], q11[8], q22[8], q12[8];
#pragma unroll
        for (int p = 0; p < 8; ++p) {
            float a1 = 0.f, a2 = 0.f, b11 = 0.f, b22 = 0.f, b12 = 0.f;
#pragma unroll
            for (int j = 0; j < KW; ++j) {
                float w = wg[j];
                a1  += w * X1(p + j);
                a2  += w * X2(p + j);
                b11 += w * p11[p + j];
                b22 += w * p22[p + j];
                b12 += w * p12[p + j];
            }
            m1[p] = a1; m2[p] = a2; q11[p] = b11; q22[p] = b22; q12[p] = b12;
        }
#undef X1
#undef X2
        const int ho = r * HPITCH + q * 8;
        *(f4*)&h1[ho]      = (f4){m1[0], m1[1], m1[2], m1[3]};
        *(f4*)&h1[ho + 4]  = (f4){m1[4], m1[5], m1[6], m1[7]};
        *(f4*)&h2[ho]      = (f4){m2[0], m2[1], m2[2], m2[3]};
        *(f4*)&h2[ho + 4]  = (f4){m2[4], m2[5], m2[6], m2[7]};
        *(f4*)&h11[ho]     = (f4){q11[0], q11[1], q11[2], q11[3]};
        *(f4*)&h11[ho + 4] = (f4){q11[4], q11[5], q11[6], q11[7]};
        *(f4*)&h22[ho]     = (f4){q22[0], q22[1], q22[2], q22[3]};
        *(f4*)&h22[ho + 4] = (f4){q22[4], q22[5], q22[6], q22[7]};
        *(f4*)&h12[ho]     = (f4){q12[0], q12[1], q12[2], q12[3]};
        *(f4*)&h12[ho + 4] = (f4){q12[4], q12[5], q12[6], q12[7]};
    }
    __syncthreads();

    // ---- Phase 2: vertical 11-tap; 128 tasks of 2 rows x 4 cols, b128 reads.
    const float C1v = 0.0001f;
    const float C2v = 0.0009f;
    float lsum = 0.f;
    if (t < 128) {
        const int rb = t >> 3, q = t & 7;         // r0 = 2*rb, cols 4q..4q+3
        const int r0 = rb * 2;
        f4 amu1[2] = {{0,0,0,0},{0,0,0,0}};
        f4 amu2[2] = {{0,0,0,0},{0,0,0,0}};
        f4 a11[2]  = {{0,0,0,0},{0,0,0,0}};
        f4 a22[2]  = {{0,0,0,0},{0,0,0,0}};
        f4 a12[2]  = {{0,0,0,0},{0,0,0,0}};
#pragma unroll
        for (int i = 0; i < 12; ++i) {
            const int o = (r0 + i) * HPITCH + q * 4;
            f4 v1 = *(const f4*)&h1[o];
            f4 v2 = *(const f4*)&h2[o];
            f4 w11 = *(const f4*)&h11[o];
            f4 w22 = *(const f4*)&h22[o];
            f4 w12 = *(const f4*)&h12[o];
#pragma unroll
            for (int k = 0; k < 2; ++k) {
                const int j = i - k;
                if (j >= 0 && j < KW) {
                    float w = wg[j];
                    amu1[k] += w * v1;
                    amu2[k] += w * v2;
                    a11[k]  += w * w11;
                    a22[k]  += w * w22;
                    a12[k]  += w * w12;
                }
            }
        }
#pragma unroll
        for (int k = 0; k < 2; ++k) {
#pragma unroll
            for (int e = 0; e < 4; ++e) {
                float mu1 = amu1[k][e], mu2 = amu2[k][e];
                float mu1sq = mu1 * mu1, mu2sq = mu2 * mu2, mu12 = mu1 * mu2;
                float sig1 = a11[k][e] - mu1sq;
                float sig2 = a22[k][e] - mu2sq;
                float sig12 = a12[k][e] - mu12;
                float num = (2.f * mu12 + C1v) * (2.f * sig12 + C2v);
                float den = (mu1sq + mu2sq + C1v) * (sig1 + sig2 + C2v);
                float r = __builtin_amdgcn_rcpf(den);
                r = r * (2.f - den * r);          // Newton step -> ~fp32 exact
                lsum += num * r;
            }
        }
    }

    // ---- Reduction: wave shuffle -> cross-wave LDS -> device atomic.
#pragma unroll
    for (int off = 32; off > 0; off >>= 1) lsum += __shfl_down(lsum, off, 64);
    if ((t & 63) == 0) wsum[t >> 6] = lsum;
    __syncthreads();
    if (t == 0) {
        float b = wsum[0] + wsum[1] + wsum[2] + wsum[3];
        atomicAdd(acc, (double)b);
        __threadfence();
        unsigned old = atomicAdd(counter, 1u);
        if (old == nblocks - 1) {
            double s = atomicAdd(acc, 0.0);       // coherent read of final sum
            out[0] = (float)(s * inv_n);
        }
    }
}

extern "C" void kernel_launch(void* const* d_in, const int* in_sizes, int n_in,
                              void* d_out, int out_size, void* d_ws, size_t ws_size,
                              hipStream_t stream) {
    const float* img1   = (const float*)d_in[0];
    const float* img2   = (const float*)d_in[1];
    const float* window = (const float*)d_in[2];
    float* out = (float*)d_out;
    double* acc = (double*)d_ws;
    unsigned* counter = (unsigned*)((char*)d_ws + 8);

    const int nplanes = in_sizes[0] / (IMH * IMW);   // 48
    const long long total = (long long)in_sizes[0];
    const unsigned nblocks = (IMW / TW) * (IMH / TH) * nplanes;

    hipMemsetAsync(d_ws, 0, 16, stream);
    dim3 grid(IMW / TW, IMH / TH, nplanes);
    ssim_main<<<grid, 256, 0, stream>>>(img1, img2, window, acc, counter, out,
                                        nblocks, 1.0 / (double)total);
}